// Round 1
// baseline (16.618 us; speedup 1.0000x reference)
//
#include <hip/hip_runtime.h>

// out[n, :] = segment_sum(segment_softmax(x, tgt), tgt)[n, :]
//           = 1.0 if node n has >=1 incoming edge, else 0.0.
// The softmax-normalized edge values summed over their own segment are
// identically s/s = 1; empty segments give segment_sum = 0.
// So we never touch x (327 MB) at all.

#define D_FEAT 128

__global__ void mark_kernel(const int* __restrict__ tgt, int* __restrict__ present, int E) {
    int i = blockIdx.x * blockDim.x + threadIdx.x;
    if (i < E) {
        // idempotent store of the same value -> no atomic needed
        present[tgt[i]] = 1;
    }
}

__global__ void write_kernel(const int* __restrict__ present, float4* __restrict__ out, int total4) {
    int i = blockIdx.x * blockDim.x + threadIdx.x;
    if (i < total4) {
        // D_FEAT/4 = 32 float4 per node -> node index = i >> 5
        int n = i >> 5;
        float v = present[n] ? 1.0f : 0.0f;
        out[i] = make_float4(v, v, v, v);
    }
}

extern "C" void kernel_launch(void* const* d_in, const int* in_sizes, int n_in,
                              void* d_out, int out_size, void* d_ws, size_t ws_size,
                              hipStream_t stream) {
    // d_in[0]: x, float32 [E, 128]  (unused)
    // d_in[1]: edge_index, int32 [2, E] row-major; row 1 = targets
    const int E = in_sizes[0] / D_FEAT;       // 640000
    const int N = out_size / D_FEAT;          // 10000

    const int* edge_index = (const int*)d_in[1];
    const int* tgt = edge_index + E;          // second row

    int* present = (int*)d_ws;                // N ints of scratch

    // Re-zero scratch every call (harness does not re-poison between replays).
    hipMemsetAsync(present, 0, (size_t)N * sizeof(int), stream);

    const int blk = 256;
    mark_kernel<<<(E + blk - 1) / blk, blk, 0, stream>>>(tgt, present, E);

    int total4 = out_size / 4;                // float4 elements
    write_kernel<<<(total4 + blk - 1) / blk, blk, 0, stream>>>(present, (float4*)d_out, total4);
}